// Round 2
// baseline (376.462 us; speedup 1.0000x reference)
//
#include <hip/hip_runtime.h>

// RoIAlign forward, Detectron-style, sampling_ratio = 2.
// features: [N=2, C=256, H=200, W=200] fp32
// rois:     [num_rois, 5] fp32 (batch_idx, x1, y1, x2, y2) image space
// out:      [num_rois, C, 7, 7] fp32
//
// R2 strategy: block = (roi, 4-channel group). Stage the roi's feature
// patch (<=43x43 px/channel) into LDS with coalesced flat-index loads,
// then sample the 16 bilinear taps per output from LDS.
// R1 was VMEM-transaction bound: 16 scattered 4B taps/output -> ~100M
// line transactions. Staging converts that to ~1/16 line per element.

#define POOLED_H 7
#define POOLED_W 7
#define SPATIAL_SCALE 0.0625f
#define FEAT_C 256
#define FEAT_H 200
#define FEAT_W 200

#define G 4            // channels per block
#define MAXD 43        // max patch rows/cols (span<=38.1 + margins)
#define MAXP (MAXD * MAXD)  // 1849 floats per channel slab (odd -> no systematic LDS conflicts)

__global__ __launch_bounds__(256) void roialign_kernel(
    const float* __restrict__ features,
    const float* __restrict__ rois,
    float* __restrict__ out,
    int num_rois) {
    __shared__ float patch[G * MAXP];

    const int blk = blockIdx.x;
    const int roi = blk >> 6;          // 256/G = 64 channel groups
    const int cg = blk & 63;
    const int cbase = cg * G;
    if (roi >= num_rois) return;

    const float* r = rois + roi * 5;
    const int b = (int)r[0];
    const float x1 = r[1] * SPATIAL_SCALE;
    const float y1 = r[2] * SPATIAL_SCALE;
    const float x2 = r[3] * SPATIAL_SCALE;
    const float y2 = r[4] * SPATIAL_SCALE;
    const float roi_w = fmaxf(x2 - x1, 1.0f);
    const float roi_h = fmaxf(y2 - y1, 1.0f);
    const float bin_w = roi_w * (1.0f / POOLED_W);
    const float bin_h = roi_h * (1.0f / POOLED_H);

    // Sample coord formula (identical at bounds-site and sample-site):
    //   coord(base, p, i) = base + p*bin + (i+0.5)*bin*0.5
    const float ymin = y1 + 0.0f * bin_h + 0.5f * bin_h * 0.5f;
    const float ymax = y1 + 6.0f * bin_h + 1.5f * bin_h * 0.5f;
    const float xmin = x1 + 0.0f * bin_w + 0.5f * bin_w * 0.5f;
    const float xmax = x1 + 6.0f * bin_w + 1.5f * bin_w * 0.5f;

    int r0 = max(0, (int)floorf(ymin) - 1);
    int r1i = min(FEAT_H - 1, (int)floorf(ymax) + 2);
    int c0 = max(0, (int)floorf(xmin) - 1);
    int c1i = min(FEAT_W - 1, (int)floorf(xmax) + 2);
    r1i = min(r1i, r0 + (MAXD - 1));
    c1i = min(c1i, c0 + (MAXD - 1));
    const int rows = r1i - r0 + 1;
    const int cols = c1i - c0 + 1;
    const int cnt = rows * cols;

    // --- stage patch: coalesced flat-index loads ---
#pragma unroll
    for (int ch = 0; ch < G; ++ch) {
        const float* plane = features +
            ((size_t)(b * FEAT_C + cbase + ch) * FEAT_H + r0) * FEAT_W + c0;
        float* dst = patch + ch * MAXP;
        for (int idx = threadIdx.x; idx < cnt; idx += 256) {
            int rr = idx / cols;
            int cc = idx - rr * cols;
            dst[idx] = plane[rr * FEAT_W + cc];
        }
    }
    __syncthreads();

    // --- compute: one output per thread (G*49 = 196 <= 256) ---
    const int o = threadIdx.x;
    if (o < G * POOLED_H * POOLED_W) {
        const int ch = o / 49;
        const int s = o - ch * 49;
        const int ph = s / POOLED_W;
        const int pw = s - ph * POOLED_W;
        const float* pp = patch + ch * MAXP;

        float acc = 0.0f;
#pragma unroll
        for (int iy = 0; iy < 2; ++iy) {
            float yy = y1 + (float)ph * bin_h + ((float)iy + 0.5f) * bin_h * 0.5f;
#pragma unroll
            for (int ix = 0; ix < 2; ++ix) {
                float xx = x1 + (float)pw * bin_w + ((float)ix + 0.5f) * bin_w * 0.5f;
                // reference-exact bilinear (valid window, lower clip, edge snap)
                bool valid = (yy > -1.0f) && (yy < (float)FEAT_H) &&
                             (xx > -1.0f) && (xx < (float)FEAT_W);
                float y = fmaxf(yy, 0.0f);
                float x = fmaxf(xx, 0.0f);
                int y0 = min((int)floorf(y), FEAT_H - 1);
                int x0 = min((int)floorf(x), FEAT_W - 1);
                int y1t = min(y0 + 1, FEAT_H - 1);
                int x1t = min(x0 + 1, FEAT_W - 1);
                if (y0 >= FEAT_H - 1) y = (float)y0;
                if (x0 >= FEAT_W - 1) x = (float)x0;
                float ly = y - (float)y0;
                float lx = x - (float)x0;
                float hy = 1.0f - ly;
                float hx = 1.0f - lx;
                int ra = (y0 - r0) * cols;
                int rb = (y1t - r0) * cols;
                int ca = x0 - c0;
                int cb = x1t - c0;
                float v00 = pp[ra + ca];
                float v01 = pp[ra + cb];
                float v10 = pp[rb + ca];
                float v11 = pp[rb + cb];
                float v = hy * (hx * v00 + lx * v01) + ly * (hx * v10 + lx * v11);
                acc += valid ? v : 0.0f;
            }
        }
        size_t oidx = (size_t)(roi * FEAT_C + cbase + ch) * 49 + s;
        out[oidx] = acc * 0.25f;
    }
}

extern "C" void kernel_launch(void* const* d_in, const int* in_sizes, int n_in,
                              void* d_out, int out_size, void* d_ws, size_t ws_size,
                              hipStream_t stream) {
    const float* features = (const float*)d_in[0];
    const float* rois = (const float*)d_in[1];
    float* out = (float*)d_out;
    int num_rois = in_sizes[1] / 5;
    int grid = num_rois * (FEAT_C / G);  // 64 channel groups per roi
    roialign_kernel<<<grid, 256, 0, stream>>>(features, rois, out, num_rois);
}

// Round 3
// 253.546 us; speedup vs baseline: 1.4848x; 1.4848x over previous
//
#include <hip/hip_runtime.h>

// RoIAlign forward, Detectron-style, sampling_ratio = 2.
// features: [N=2, C=256, H=200, W=200] fp32 ; rois: [1000,5] ; out: [1000,256,7,7]
//
// R3 strategy: tap indices/weights are channel-independent, so convert the
// gather into coalesced reads by transposing features to NHWC in d_ws.
// Main kernel: one wave per (roi, spatial cell); lane L covers channels
// 4L..4L+3 via float4. Each of the 16 bilinear taps is one fully-coalesced
// 1 KB wave load. R1 was VMEM-transaction bound (~69M line transactions);
// this needs ~12.5M read + ~12.5M store transactions.

#define POOLED_H 7
#define POOLED_W 7
#define SPATIAL_SCALE 0.0625f
#define FEAT_N 2
#define FEAT_C 256
#define FEAT_H 200
#define FEAT_W 200
#define FEAT_S (FEAT_H * FEAT_W)   // 40000

// ---------------- transpose NCHW -> NHWC ----------------
#define TILE 64
__global__ __launch_bounds__(256) void nchw_to_nhwc(const float* __restrict__ in,
                                                    float* __restrict__ outp) {
    __shared__ float t[TILE][TILE + 1];
    const int s0 = blockIdx.x * TILE;   // spatial tile (625 tiles, exact)
    const int c0 = blockIdx.y * TILE;   // channel tile (4 tiles, exact)
    const int b = blockIdx.z;
    const int j = threadIdx.x & 63;
    const int i0 = threadIdx.x >> 6;    // 0..3
    const float* ip = in + ((size_t)(b * FEAT_C + c0)) * FEAT_S + s0;
#pragma unroll
    for (int k = 0; k < 16; ++k) {
        int i = i0 + k * 4;
        t[i][j] = ip[(size_t)i * FEAT_S + j];   // coalesced along s
    }
    __syncthreads();
    float* op = outp + ((size_t)b * FEAT_S + s0) * FEAT_C + c0;
#pragma unroll
    for (int k = 0; k < 16; ++k) {
        int jj = i0 + k * 4;
        op[(size_t)jj * FEAT_C + j] = t[j][jj]; // coalesced along c, stride-65 LDS reads
    }
}

// ---------------- main NHWC kernel ----------------
__global__ __launch_bounds__(256) void roialign_nhwc(
    const float* __restrict__ feat,   // [N, H, W, C]
    const float* __restrict__ rois,
    float* __restrict__ out,
    int num_rois) {
    const int wid = blockIdx.x * 4 + (threadIdx.x >> 6);
    const int lane = threadIdx.x & 63;
    const int roi = wid / 49;
    const int s = wid - roi * 49;
    if (roi >= num_rois) return;
    const int ph = s / POOLED_W;
    const int pw = s - ph * POOLED_W;

    const float* r = rois + roi * 5;
    const int b = (int)r[0];
    const float x1 = r[1] * SPATIAL_SCALE;
    const float y1 = r[2] * SPATIAL_SCALE;
    const float x2 = r[3] * SPATIAL_SCALE;
    const float y2 = r[4] * SPATIAL_SCALE;
    const float roi_w = fmaxf(x2 - x1, 1.0f);
    const float roi_h = fmaxf(y2 - y1, 1.0f);
    const float bin_w = roi_w * (1.0f / POOLED_W);
    const float bin_h = roi_h * (1.0f / POOLED_H);

    // per-axis sample info (2 samples each axis), reference-exact
    int yl[2], yh[2];
    float wly[2], why[2];
    bool vy[2];
#pragma unroll
    for (int iy = 0; iy < 2; ++iy) {
        float yy = y1 + (float)ph * bin_h + ((float)iy + 0.5f) * bin_h * 0.5f;
        vy[iy] = (yy > -1.0f) && (yy < (float)FEAT_H);
        float y = fmaxf(yy, 0.0f);
        int y0 = min((int)floorf(y), FEAT_H - 1);
        int y1t = min(y0 + 1, FEAT_H - 1);
        if (y0 >= FEAT_H - 1) y = (float)y0;
        yl[iy] = y0; yh[iy] = y1t;
        wly[iy] = y - (float)y0;
        why[iy] = 1.0f - wly[iy];
    }
    int xl[2], xh[2];
    float wlx[2], whx[2];
    bool vx[2];
#pragma unroll
    for (int ix = 0; ix < 2; ++ix) {
        float xx = x1 + (float)pw * bin_w + ((float)ix + 0.5f) * bin_w * 0.5f;
        vx[ix] = (xx > -1.0f) && (xx < (float)FEAT_W);
        float x = fmaxf(xx, 0.0f);
        int x0 = min((int)floorf(x), FEAT_W - 1);
        int x1t = min(x0 + 1, FEAT_W - 1);
        if (x0 >= FEAT_W - 1) x = (float)x0;
        xl[ix] = x0; xh[ix] = x1t;
        wlx[ix] = x - (float)x0;
        whx[ix] = 1.0f - wlx[ix];
    }

    const float* base = feat + (size_t)b * FEAT_S * FEAT_C + lane * 4;
    float ax = 0.0f, ay = 0.0f, az = 0.0f, aw = 0.0f;
#pragma unroll
    for (int iy = 0; iy < 2; ++iy) {
#pragma unroll
        for (int ix = 0; ix < 2; ++ix) {
            const float m = (vy[iy] && vx[ix]) ? 1.0f : 0.0f;
            const float w00 = m * why[iy] * whx[ix];
            const float w01 = m * why[iy] * wlx[ix];
            const float w10 = m * wly[iy] * whx[ix];
            const float w11 = m * wly[iy] * wlx[ix];
            const int ra = yl[iy] * FEAT_W, rb = yh[iy] * FEAT_W;
            const float4 v00 = *(const float4*)(base + (size_t)(ra + xl[ix]) * FEAT_C);
            const float4 v01 = *(const float4*)(base + (size_t)(ra + xh[ix]) * FEAT_C);
            const float4 v10 = *(const float4*)(base + (size_t)(rb + xl[ix]) * FEAT_C);
            const float4 v11 = *(const float4*)(base + (size_t)(rb + xh[ix]) * FEAT_C);
            ax += w00 * v00.x + w01 * v01.x + w10 * v10.x + w11 * v11.x;
            ay += w00 * v00.y + w01 * v01.y + w10 * v10.y + w11 * v11.y;
            az += w00 * v00.z + w01 * v01.z + w10 * v10.z + w11 * v11.z;
            aw += w00 * v00.w + w01 * v01.w + w10 * v10.w + w11 * v11.w;
        }
    }
    float* ob = out + ((size_t)roi * FEAT_C + lane * 4) * 49 + s;
    ob[0] = ax * 0.25f;
    ob[49] = ay * 0.25f;
    ob[98] = az * 0.25f;
    ob[147] = aw * 0.25f;
}

// ---------------- fallback (R1 direct-gather) ----------------
__device__ __forceinline__ float bilinear_tap(const float* __restrict__ plane,
                                              float y, float x) {
    const int H = FEAT_H, W = FEAT_W;
    if (!(y > -1.0f && y < (float)H && x > -1.0f && x < (float)W)) return 0.0f;
    y = fmaxf(y, 0.0f);
    x = fmaxf(x, 0.0f);
    int y0 = min((int)floorf(y), H - 1);
    int x0 = min((int)floorf(x), W - 1);
    int y1 = min(y0 + 1, H - 1);
    int x1 = min(x0 + 1, W - 1);
    if (y0 >= H - 1) y = (float)y0;
    if (x0 >= W - 1) x = (float)x0;
    float ly = y - (float)y0, lx = x - (float)x0;
    float hy = 1.0f - ly, hx = 1.0f - lx;
    return hy * (hx * plane[y0 * W + x0] + lx * plane[y0 * W + x1]) +
           ly * (hx * plane[y1 * W + x0] + lx * plane[y1 * W + x1]);
}

__global__ __launch_bounds__(256) void roialign_direct(
    const float* __restrict__ features, const float* __restrict__ rois,
    float* __restrict__ out, int num_rois) {
    int i = blockIdx.x * blockDim.x + threadIdx.x;
    int total = num_rois * FEAT_C * 49;
    if (i >= total) return;
    int s = i % 49;
    int t = i / 49;
    int c = t % FEAT_C;
    int roi = t / FEAT_C;
    int ph = s / POOLED_W, pw = s % POOLED_W;
    const float* r = rois + roi * 5;
    int b = (int)r[0];
    float x1 = r[1] * SPATIAL_SCALE, y1 = r[2] * SPATIAL_SCALE;
    float x2 = r[3] * SPATIAL_SCALE, y2 = r[4] * SPATIAL_SCALE;
    float bin_w = fmaxf(x2 - x1, 1.0f) * (1.0f / POOLED_W);
    float bin_h = fmaxf(y2 - y1, 1.0f) * (1.0f / POOLED_H);
    const float* plane = features + ((size_t)(b * FEAT_C + c)) * FEAT_S;
    float acc = 0.0f;
#pragma unroll
    for (int iy = 0; iy < 2; ++iy) {
        float yy = y1 + (float)ph * bin_h + ((float)iy + 0.5f) * bin_h * 0.5f;
#pragma unroll
        for (int ix = 0; ix < 2; ++ix) {
            float xx = x1 + (float)pw * bin_w + ((float)ix + 0.5f) * bin_w * 0.5f;
            acc += bilinear_tap(plane, yy, xx);
        }
    }
    out[i] = acc * 0.25f;
}

extern "C" void kernel_launch(void* const* d_in, const int* in_sizes, int n_in,
                              void* d_out, int out_size, void* d_ws, size_t ws_size,
                              hipStream_t stream) {
    const float* features = (const float*)d_in[0];
    const float* rois = (const float*)d_in[1];
    float* out = (float*)d_out;
    int num_rois = in_sizes[1] / 5;
    size_t need = (size_t)FEAT_N * FEAT_S * FEAT_C * sizeof(float);  // 81.92 MB
    if (ws_size >= need) {
        float* nhwc = (float*)d_ws;
        nchw_to_nhwc<<<dim3(FEAT_S / TILE, FEAT_C / TILE, FEAT_N), 256, 0, stream>>>(
            features, nhwc);
        int nw = num_rois * 49;
        roialign_nhwc<<<(nw + 3) / 4, 256, 0, stream>>>(nhwc, rois, out, num_rois);
    } else {
        int total = num_rois * FEAT_C * 49;
        roialign_direct<<<(total + 255) / 256, 256, 0, stream>>>(features, rois, out,
                                                                 num_rois);
    }
}